// Round 6
// baseline (185.572 us; speedup 1.0000x reference)
//
#include <hip/hip_runtime.h>
#include <hip/hip_fp16.h>

#define NN   50000
#define FIN  256
#define C1   64        // HEADS*HID
#define NH   8
#define NHID 8
#define NC   16
#define NE   1600000
#define NTOT (NE + NN)

#define CH   256                        // pass-1 chunks
#define EPC  ((NTOT + CH - 1) / CH)     // 6446 edges per chunk
#define NCB  196                        // coarse buckets: dst>>8

typedef _Float16 half8 __attribute__((ext_vector_type(8)));
typedef float f32x4 __attribute__((ext_vector_type(4)));

// ---- workspace layout (float-indexed), ~36.0 MB total ----
#define OFF_H1H   0          // fp16 h1 [NN*64] halves; dies after k_agg1, region reused:
#define OFF_H2    0          //   h2 @0, als2 @800000, ald2 @850000
#define OFF_ALS2  800000
#define OFF_ALD2  850000
#define OFF_G1    3200000    // g1 [NN*C1] f32; aliased by `stage` during sort (NTOT ints)
#define OFF_ALS1  6400000
#define OFF_ALD1  6800000
#define OFF_HM    7200000    // int H[CH*NCB]
#define OFF_BASEK 7251000    // int basek[NCB*CH]
#define OFF_BBASE 7302000    // int bbase[NCB+1] (+btot scratch behind it)
#define OFF_OFFS  7302400    // int offs[NN+1]
#define OFF_SRC   7352500    // int ssrc[NTOT]
// end = 9,002,500 floats = 36.0 MB

// ------- K1: h1 = x @ W1 via MFMA fp16, fused fp16-store + logits epilogue --
// block = 256 (4 waves); tile 64 rows x 64 cols; K=256 in 8 steps of 32.
__global__ __launch_bounds__(256) void k_gemm1(const float* __restrict__ x,
                                               const float* __restrict__ W1,
                                               const float* __restrict__ as1,
                                               const float* __restrict__ ad1,
                                               __half* __restrict__ h1h,
                                               float* __restrict__ als,
                                               float* __restrict__ ald) {
    __shared__ _Float16 wsT[64][264];   // [col][k], pad 256->264 halves (16B-aligned rows)
    __shared__ _Float16 xs[64][40];     // [row][k-chunk 32], pad ->40
    const int tid = threadIdx.x;
    const int r0 = blockIdx.x * 64;

    // one-time: W1 (256x64 f32, k-major) -> wsT[col][k] f16
    for (int i = tid; i < FIN * C1; i += 256) {
        int k = i >> 6, c = i & 63;
        wsT[c][k] = (_Float16)W1[i];
    }

    const int lane = tid & 63;
    const int wv   = tid >> 6;          // wave id -> rows wv*16..+16
    const int colb = lane & 15;
    const int rgrp = lane >> 4;
    f32x4 acc[4] = {};

    const int srow = tid >> 2;          // staging row
    const int sq   = tid & 3;           // staging quad (8 floats)
    for (int k0 = 0; k0 < FIN; k0 += 32) {
        __syncthreads();                // protect xs from prev reads / wsT first pass
        {
            int grow = r0 + srow;
            float4 v0 = make_float4(0.f,0.f,0.f,0.f), v1 = v0;
            if (grow < NN) {
                const float4* xp = (const float4*)(&x[(size_t)grow * FIN + k0 + sq * 8]);
                v0 = xp[0]; v1 = xp[1];
            }
            half8 hv;
            hv[0]=(_Float16)v0.x; hv[1]=(_Float16)v0.y; hv[2]=(_Float16)v0.z; hv[3]=(_Float16)v0.w;
            hv[4]=(_Float16)v1.x; hv[5]=(_Float16)v1.y; hv[6]=(_Float16)v1.z; hv[7]=(_Float16)v1.w;
            *(half8*)(&xs[srow][sq * 8]) = hv;
        }
        __syncthreads();
        half8 a = *(half8*)(&xs[wv * 16 + colb][rgrp * 8]);
        #pragma unroll
        for (int ct = 0; ct < 4; ++ct) {
            half8 b = *(half8*)(&wsT[ct * 16 + colb][k0 + rgrp * 8]);
            acc[ct] = __builtin_amdgcn_mfma_f32_16x16x32_f16(a, b, acc[ct], 0, 0, 0);
        }
    }

    // epilogue: C/D layout col = lane&15 (+ct*16), row = rgrp*4 + j (+wv*16)
    float a_s[4], a_d[4];
    #pragma unroll
    for (int ct = 0; ct < 4; ++ct) { a_s[ct] = as1[ct * 16 + colb]; a_d[ct] = ad1[ct * 16 + colb]; }
    #pragma unroll
    for (int j = 0; j < 4; ++j) {
        int row = r0 + wv * 16 + rgrp * 4 + j;
        bool rv = row < NN;
        #pragma unroll
        for (int ct = 0; ct < 4; ++ct) {
            if (rv) h1h[(size_t)row * C1 + ct * 16 + colb] = __float2half(acc[ct][j]);
            float p = acc[ct][j] * a_s[ct];
            p += __shfl_xor(p, 1); p += __shfl_xor(p, 2); p += __shfl_xor(p, 4);
            float q = acc[ct][j] * a_d[ct];
            q += __shfl_xor(q, 1); q += __shfl_xor(q, 2); q += __shfl_xor(q, 4);
            if (rv && (lane & 7) == 0) {
                int head = ct * 2 + (colb >> 3);
                als[row * NH + head] = p;
                ald[row * NH + head] = q;
            }
        }
    }
}

// ======== deterministic 2-pass counting sort (no global atomics) =========
__global__ __launch_bounds__(256) void k_rh(const int* __restrict__ ei,
                                            int* __restrict__ H) {
    __shared__ int lh[NCB];
    int k = blockIdx.x;
    for (int i = threadIdx.x; i < NCB; i += 256) lh[i] = 0;
    __syncthreads();
    int e0 = k * EPC, e1 = min(e0 + EPC, NTOT);
    for (int e = e0 + threadIdx.x; e < e1; e += 256) {
        int d = (e < NE) ? ei[NE + e] : (e - NE);
        atomicAdd(&lh[d >> 8], 1);
    }
    __syncthreads();
    for (int i = threadIdx.x; i < NCB; i += 256) H[k * NCB + i] = lh[i];
}

__global__ __launch_bounds__(256) void k_rsA(const int* __restrict__ H,
                                             int* __restrict__ basek,
                                             int* __restrict__ btot) {
    __shared__ int sc[CH];
    int b = blockIdx.x, t = threadIdx.x;
    int v = H[t * NCB + b];
    sc[t] = v;
    __syncthreads();
    for (int s = 1; s < CH; s <<= 1) {
        int u = (t >= s) ? sc[t - s] : 0;
        __syncthreads();
        sc[t] += u;
        __syncthreads();
    }
    basek[b * CH + t] = sc[t] - v;
    if (t == CH - 1) btot[b] = sc[t];
}

__global__ __launch_bounds__(64) void k_rsB(int* __restrict__ btot,
                                            int* __restrict__ bbase,
                                            int* __restrict__ offs) {
    if (threadIdx.x == 0) {
        int run = 0;
        for (int b = 0; b < NCB; ++b) {
            bbase[b] = run;
            run += btot[b];
        }
        bbase[NCB] = run;
        offs[NN] = NTOT;
    }
}

__global__ __launch_bounds__(256) void k_rscatter(const int* __restrict__ ei,
                                                  const int* __restrict__ basek,
                                                  const int* __restrict__ bbase,
                                                  int* __restrict__ stage) {
    __shared__ int lcur[NCB];
    int k = blockIdx.x;
    for (int i = threadIdx.x; i < NCB; i += 256)
        lcur[i] = bbase[i] + basek[i * CH + k];
    __syncthreads();
    int e0 = k * EPC, e1 = min(e0 + EPC, NTOT);
    for (int e = e0 + threadIdx.x; e < e1; e += 256) {
        int s, d;
        if (e < NE) { s = ei[e]; d = ei[NE + e]; }
        else        { s = e - NE; d = s; }
        int pos = atomicAdd(&lcur[d >> 8], 1);
        stage[pos] = (s << 8) | (d & 255);
    }
}

__global__ __launch_bounds__(256) void k_fsort(const int* __restrict__ stage,
                                               const int* __restrict__ bbase,
                                               int* __restrict__ offs,
                                               int* __restrict__ ssrc) {
    __shared__ int lc[256];
    __shared__ int ls[256];
    __shared__ int lcur[256];
    int b = blockIdx.x, t = threadIdx.x;
    int base = bbase[b];
    int n = bbase[b + 1] - base;
    lc[t] = 0;
    __syncthreads();
    const int* sp = &stage[base];
    for (int i = t; i < n; i += 256) atomicAdd(&lc[sp[i] & 255], 1);
    __syncthreads();
    int v = lc[t];
    ls[t] = v;
    __syncthreads();
    for (int s = 1; s < 256; s <<= 1) {
        int u = (t >= s) ? ls[t - s] : 0;
        __syncthreads();
        ls[t] += u;
        __syncthreads();
    }
    int excl = ls[t] - v;
    int d = b * 256 + t;
    if (d < NN) offs[d] = base + excl;
    lcur[t] = base + excl;
    __syncthreads();
    for (int i = t; i < n; i += 256) {
        int u = sp[i];
        int pos = atomicAdd(&lcur[u & 255], 1);
        ssrc[pos] = u >> 8;
    }
}

// ------- K2: layer-1 aggregation: 8-edge rounds, paired half2 gathers ------
// one wave per dst. weight duty: lane l -> (edge l>>3, head l&7).
// gather duty: half=l>>5, cp=l&31 -> channels 2cp,2cp+1 (head cp>>2) of edge 2i+half.
__global__ __launch_bounds__(256) void k_agg1(const int* __restrict__ offs,
                                              const int* __restrict__ src,
                                              const __half* __restrict__ h1h,
                                              const float* __restrict__ als,
                                              const float* __restrict__ ald,
                                              const float* __restrict__ b1,
                                              float* __restrict__ g1) {
    int d = blockIdx.x * 4 + (threadIdx.x >> 6);
    if (d >= NN) return;
    const int l = threadIdx.x & 63;
    const int sub = l >> 3, hh = l & 7;
    const int hf = l >> 5, cp = l & 31;
    const int hp = cp >> 2;
    int beg = offs[d], end = offs[d + 1];
    float aldv = ald[d * NH + hh];
    float accx = 0.f, accy = 0.f, den = 0.f;
    for (int r = beg; r < end; r += 8) {
        int e = r + sub;
        bool valid = e < end;
        int s_my = src[valid ? e : end - 1];
        float lg = als[s_my * NH + hh] + aldv;
        lg = lg > 0.f ? lg : 0.2f * lg;
        float w = valid ? __expf(lg) : 0.f;
        #pragma unroll
        for (int i = 0; i < 4; ++i) {
            int srcl = (2 * i + hf) * 8;
            int sv   = __shfl(s_my, srcl);
            float wv = __shfl(w, srcl + hp);
            __half2 hv = *(const __half2*)(&h1h[(size_t)sv * C1 + 2 * cp]);
            float2 hfv = __half22float2(hv);
            accx += wv * hfv.x;
            accy += wv * hfv.y;
            den  += wv;
        }
    }
    accx += __shfl_xor(accx, 32);
    accy += __shfl_xor(accy, 32);
    den  += __shfl_xor(den, 32);
    float o0 = accx / den + b1[2 * cp];
    float o1 = accy / den + b1[2 * cp + 1];
    o0 = o0 > 0.f ? o0 : (__expf(o0) - 1.f);
    o1 = o1 > 0.f ? o1 : (__expf(o1) - 1.f);
    if (hf == 0)
        *(float2*)(&g1[(size_t)d * C1 + 2 * cp]) = make_float2(o0, o1);
}

// ---------------- K3: GEMM2 (64->16) + layer-2 logits ----------------
__global__ __launch_bounds__(256) void k_gemm2(const float* __restrict__ g1,
                                               const float* __restrict__ W2,
                                               const float* __restrict__ as2,
                                               const float* __restrict__ ad2,
                                               float* __restrict__ h2,
                                               float* __restrict__ als2,
                                               float* __restrict__ ald2) {
    __shared__ float w2s[C1][NC];
    __shared__ float hact[16][C1 + 4];
    int tid = threadIdx.x;
    for (int i = tid; i < C1 * NC; i += 256) w2s[i >> 4][i & 15] = W2[i];
    int ln = tid >> 4, j = tid & 15;
    int n = blockIdx.x * 16 + ln;
    if (n < NN) {
        float4 v = *(const float4*)(&g1[(size_t)n * C1 + j * 4]);
        *(float4*)(&hact[ln][j * 4]) = v;
    }
    __syncthreads();
    if (n < NN) {
        float sum = 0.f;
        #pragma unroll
        for (int c = 0; c < C1; ++c) sum += hact[ln][c] * w2s[c][j];
        h2[(size_t)n * NC + j] = sum;
        float ps = sum * as2[j], pd = sum * ad2[j];
        #pragma unroll
        for (int w = 1; w < 16; w <<= 1) {
            ps += __shfl_xor(ps, w);
            pd += __shfl_xor(pd, w);
        }
        if (j == 0) { als2[n] = ps; ald2[n] = pd; }
    }
}

// ------- K4: layer-2 aggregation, wave-per-dst, 4 edges/iter + log_softmax --
__global__ __launch_bounds__(256) void k_agg2(const int* __restrict__ offs,
                                              const int* __restrict__ src,
                                              const float* __restrict__ h2,
                                              const float* __restrict__ als2,
                                              const float* __restrict__ ald2,
                                              const float* __restrict__ b2,
                                              float* __restrict__ out) {
    int d = blockIdx.x * 4 + (threadIdx.x >> 6);
    if (d >= NN) return;
    int l = threadIdx.x & 63;
    int es = l >> 4, c = l & 15;
    int beg = offs[d], end = offs[d + 1];
    float aldv = ald2[d];
    float acc = 0.f, den = 0.f;
    for (int r = beg; r < end; r += 4) {
        int e = r + es;
        bool valid = e < end;
        int s = src[valid ? e : end - 1];
        float lg = als2[s] + aldv;
        lg = lg > 0.f ? lg : 0.2f * lg;
        float w = valid ? __expf(lg) : 0.f;
        float hv = h2[(size_t)s * NC + c];
        acc += w * hv;
        den += w;
    }
    acc += __shfl_xor(acc, 16); acc += __shfl_xor(acc, 32);
    den += __shfl_xor(den, 16); den += __shfl_xor(den, 32);
    float o = acc / den + b2[c];
    float m = o;
    #pragma unroll
    for (int w = 1; w < 16; w <<= 1) m = fmaxf(m, __shfl_xor(m, w));
    float ex = __expf(o - m);
    float sm = ex;
    #pragma unroll
    for (int w = 1; w < 16; w <<= 1) sm += __shfl_xor(sm, w);
    if (l < 16) out[(size_t)d * NC + c] = o - m - __logf(sm);
}

extern "C" void kernel_launch(void* const* d_in, const int* in_sizes, int n_in,
                              void* d_out, int out_size, void* d_ws, size_t ws_size,
                              hipStream_t stream) {
    const float* x   = (const float*)d_in[0];
    const int*   ei  = (const int*)  d_in[1];
    const float* W1  = (const float*)d_in[2];
    const float* as1 = (const float*)d_in[3];
    const float* ad1 = (const float*)d_in[4];
    const float* b1  = (const float*)d_in[5];
    const float* W2  = (const float*)d_in[6];
    const float* as2 = (const float*)d_in[7];
    const float* ad2 = (const float*)d_in[8];
    const float* b2  = (const float*)d_in[9];
    float* ws  = (float*)d_ws;
    float* out = (float*)d_out;

    __half* h1h = (__half*)(ws + OFF_H1H);
    float* g1   = ws + OFF_G1;
    float* als1 = ws + OFF_ALS1;
    float* ald1 = ws + OFF_ALD1;
    float* h2   = ws + OFF_H2;
    float* als2 = ws + OFF_ALS2;
    float* ald2 = ws + OFF_ALD2;
    int* H      = (int*)(ws + OFF_HM);
    int* basek  = (int*)(ws + OFF_BASEK);
    int* bbase  = (int*)(ws + OFF_BBASE);
    int* offs   = (int*)(ws + OFF_OFFS);
    int* ssrc   = (int*)(ws + OFF_SRC);
    int* stage  = (int*)(ws + OFF_G1);   // aliases g1 (dead before k_agg1 writes g1)

    k_gemm1   <<<(NN + 63) / 64, 256, 0, stream>>>(x, W1, as1, ad1, h1h, als1, ald1);
    k_rh      <<<CH,             256, 0, stream>>>(ei, H);
    k_rsA     <<<NCB,            256, 0, stream>>>(H, basek, bbase + NCB + 2 /*btot*/);
    k_rsB     <<<1,               64, 0, stream>>>(bbase + NCB + 2, bbase, offs);
    k_rscatter<<<CH,             256, 0, stream>>>(ei, basek, bbase, stage);
    k_fsort   <<<NCB,            256, 0, stream>>>(stage, bbase, offs, ssrc);
    k_agg1    <<<(NN + 3) / 4,   256, 0, stream>>>(offs, ssrc, h1h, als1, ald1, b1, g1);
    k_gemm2   <<<(NN + 15) / 16, 256, 0, stream>>>(g1, W2, as2, ad2, h2, als2, ald2);
    k_agg2    <<<(NN + 3) / 4,   256, 0, stream>>>(offs, ssrc, h2, als2, ald2, b2, out);
}

// Round 7
// 148.828 us; speedup vs baseline: 1.2469x; 1.2469x over previous
//
#include <hip/hip_runtime.h>
#include <hip/hip_fp16.h>

#define NN   50000
#define FIN  256
#define C1   64        // HEADS*HID
#define NH   8
#define NHID 8
#define NC   16
#define NE   1600000
#define NTOT (NE + NN)

#define CH   256                        // pass-1 chunks
#define EPC  ((NTOT + CH - 1) / CH)     // 6446 edges per chunk
#define NCB  196                        // coarse buckets: dst>>8

typedef _Float16 half8 __attribute__((ext_vector_type(8)));
typedef float f32x4 __attribute__((ext_vector_type(4)));

// ---- workspace layout (float-indexed), ~36.0 MB total ----
#define OFF_H1H   0          // fp16 h1 [NN*64] halves; dies after k_agg1, region reused:
#define OFF_H2    0          //   h2 @0, als2 @800000, ald2 @850000
#define OFF_ALS2  800000
#define OFF_ALD2  850000
#define OFF_G1    3200000    // g1 [NN*C1] f32; aliased by `stage` during sort (NTOT ints)
#define OFF_ALS1  6400000
#define OFF_ALD1  6800000
#define OFF_HM    7200000    // int H[CH*NCB]
#define OFF_BASEK 7251000    // int basek[NCB*CH]
#define OFF_BBASE 7302000    // int bbase[NCB+1] (+btot scratch behind it)
#define OFF_OFFS  7302400    // int offs[NN+1]
#define OFF_SRC   7352500    // int ssrc[NTOT]
// end = 9,002,500 floats = 36.0 MB

// ------- K1: h1 = x @ W1 via MFMA fp16, fused fp16-store + logits epilogue --
__global__ __launch_bounds__(256) void k_gemm1(const float* __restrict__ x,
                                               const float* __restrict__ W1,
                                               const float* __restrict__ as1,
                                               const float* __restrict__ ad1,
                                               __half* __restrict__ h1h,
                                               float* __restrict__ als,
                                               float* __restrict__ ald) {
    __shared__ _Float16 wsT[64][264];   // [col][k], pad 256->264 halves
    __shared__ _Float16 xs[64][40];     // [row][k-chunk 32], pad ->40
    const int tid = threadIdx.x;
    const int r0 = blockIdx.x * 64;

    for (int i = tid; i < FIN * C1; i += 256) {
        int k = i >> 6, c = i & 63;
        wsT[c][k] = (_Float16)W1[i];
    }

    const int lane = tid & 63;
    const int wv   = tid >> 6;
    const int colb = lane & 15;
    const int rgrp = lane >> 4;
    f32x4 acc[4] = {};

    const int srow = tid >> 2;
    const int sq   = tid & 3;
    for (int k0 = 0; k0 < FIN; k0 += 32) {
        __syncthreads();
        {
            int grow = r0 + srow;
            float4 v0 = make_float4(0.f,0.f,0.f,0.f), v1 = v0;
            if (grow < NN) {
                const float4* xp = (const float4*)(&x[(size_t)grow * FIN + k0 + sq * 8]);
                v0 = xp[0]; v1 = xp[1];
            }
            half8 hv;
            hv[0]=(_Float16)v0.x; hv[1]=(_Float16)v0.y; hv[2]=(_Float16)v0.z; hv[3]=(_Float16)v0.w;
            hv[4]=(_Float16)v1.x; hv[5]=(_Float16)v1.y; hv[6]=(_Float16)v1.z; hv[7]=(_Float16)v1.w;
            *(half8*)(&xs[srow][sq * 8]) = hv;
        }
        __syncthreads();
        half8 a = *(half8*)(&xs[wv * 16 + colb][rgrp * 8]);
        #pragma unroll
        for (int ct = 0; ct < 4; ++ct) {
            half8 b = *(half8*)(&wsT[ct * 16 + colb][k0 + rgrp * 8]);
            acc[ct] = __builtin_amdgcn_mfma_f32_16x16x32_f16(a, b, acc[ct], 0, 0, 0);
        }
    }

    float a_s[4], a_d[4];
    #pragma unroll
    for (int ct = 0; ct < 4; ++ct) { a_s[ct] = as1[ct * 16 + colb]; a_d[ct] = ad1[ct * 16 + colb]; }
    #pragma unroll
    for (int j = 0; j < 4; ++j) {
        int row = r0 + wv * 16 + rgrp * 4 + j;
        bool rv = row < NN;
        #pragma unroll
        for (int ct = 0; ct < 4; ++ct) {
            if (rv) h1h[(size_t)row * C1 + ct * 16 + colb] = __float2half(acc[ct][j]);
            float p = acc[ct][j] * a_s[ct];
            p += __shfl_xor(p, 1); p += __shfl_xor(p, 2); p += __shfl_xor(p, 4);
            float q = acc[ct][j] * a_d[ct];
            q += __shfl_xor(q, 1); q += __shfl_xor(q, 2); q += __shfl_xor(q, 4);
            if (rv && (lane & 7) == 0) {
                int head = ct * 2 + (colb >> 3);
                als[row * NH + head] = p;
                ald[row * NH + head] = q;
            }
        }
    }
}

// ======== deterministic 2-pass counting sort (no global atomics) =========
__global__ __launch_bounds__(256) void k_rh(const int* __restrict__ ei,
                                            int* __restrict__ H) {
    __shared__ int lh[NCB];
    int k = blockIdx.x;
    for (int i = threadIdx.x; i < NCB; i += 256) lh[i] = 0;
    __syncthreads();
    int e0 = k * EPC, e1 = min(e0 + EPC, NTOT);
    for (int e = e0 + threadIdx.x; e < e1; e += 256) {
        int d = (e < NE) ? ei[NE + e] : (e - NE);
        atomicAdd(&lh[d >> 8], 1);
    }
    __syncthreads();
    for (int i = threadIdx.x; i < NCB; i += 256) H[k * NCB + i] = lh[i];
}

__global__ __launch_bounds__(256) void k_rsA(const int* __restrict__ H,
                                             int* __restrict__ basek,
                                             int* __restrict__ btot) {
    __shared__ int sc[CH];
    int b = blockIdx.x, t = threadIdx.x;
    int v = H[t * NCB + b];
    sc[t] = v;
    __syncthreads();
    for (int s = 1; s < CH; s <<= 1) {
        int u = (t >= s) ? sc[t - s] : 0;
        __syncthreads();
        sc[t] += u;
        __syncthreads();
    }
    basek[b * CH + t] = sc[t] - v;
    if (t == CH - 1) btot[b] = sc[t];
}

__global__ __launch_bounds__(64) void k_rsB(int* __restrict__ btot,
                                            int* __restrict__ bbase,
                                            int* __restrict__ offs) {
    if (threadIdx.x == 0) {
        int run = 0;
        for (int b = 0; b < NCB; ++b) {
            bbase[b] = run;
            run += btot[b];
        }
        bbase[NCB] = run;
        offs[NN] = NTOT;
    }
}

__global__ __launch_bounds__(256) void k_rscatter(const int* __restrict__ ei,
                                                  const int* __restrict__ basek,
                                                  const int* __restrict__ bbase,
                                                  int* __restrict__ stage) {
    __shared__ int lcur[NCB];
    int k = blockIdx.x;
    for (int i = threadIdx.x; i < NCB; i += 256)
        lcur[i] = bbase[i] + basek[i * CH + k];
    __syncthreads();
    int e0 = k * EPC, e1 = min(e0 + EPC, NTOT);
    for (int e = e0 + threadIdx.x; e < e1; e += 256) {
        int s, d;
        if (e < NE) { s = ei[e]; d = ei[NE + e]; }
        else        { s = e - NE; d = s; }
        int pos = atomicAdd(&lcur[d >> 8], 1);
        stage[pos] = (s << 8) | (d & 255);
    }
}

__global__ __launch_bounds__(256) void k_fsort(const int* __restrict__ stage,
                                               const int* __restrict__ bbase,
                                               int* __restrict__ offs,
                                               int* __restrict__ ssrc) {
    __shared__ int lc[256];
    __shared__ int ls[256];
    __shared__ int lcur[256];
    int b = blockIdx.x, t = threadIdx.x;
    int base = bbase[b];
    int n = bbase[b + 1] - base;
    lc[t] = 0;
    __syncthreads();
    const int* sp = &stage[base];
    for (int i = t; i < n; i += 256) atomicAdd(&lc[sp[i] & 255], 1);
    __syncthreads();
    int v = lc[t];
    ls[t] = v;
    __syncthreads();
    for (int s = 1; s < 256; s <<= 1) {
        int u = (t >= s) ? ls[t - s] : 0;
        __syncthreads();
        ls[t] += u;
        __syncthreads();
    }
    int excl = ls[t] - v;
    int d = b * 256 + t;
    if (d < NN) offs[d] = base + excl;
    lcur[t] = base + excl;
    __syncthreads();
    for (int i = t; i < n; i += 256) {
        int u = sp[i];
        int pos = atomicAdd(&lcur[u & 255], 1);
        ssrc[pos] = u >> 8;
    }
}

// ------- K2: layer-1 aggregation: 16-edge super-rounds, paired half2 gathers
// one wave per dst. lane l computes weights for edges (l>>3) and (l>>3)+8,
// head l&7; gather duty: half=l>>5 handles 8 of 16 edges, channel-pair cp=l&31.
__global__ __launch_bounds__(256) void k_agg1(const int* __restrict__ offs,
                                              const int* __restrict__ src,
                                              const __half* __restrict__ h1h,
                                              const float* __restrict__ als,
                                              const float* __restrict__ ald,
                                              const float* __restrict__ b1,
                                              float* __restrict__ g1) {
    int d = blockIdx.x * 4 + (threadIdx.x >> 6);
    if (d >= NN) return;
    const int l = threadIdx.x & 63;
    const int sub = l >> 3, hh = l & 7;
    const int hf = l >> 5, cp = l & 31;
    const int hp = cp >> 2;
    int beg = offs[d], end = offs[d + 1];
    float aldv = ald[d * NH + hh];
    float accx = 0.f, accy = 0.f, den = 0.f;
    for (int r = beg; r < end; r += 16) {
        int e0 = r + sub, e1 = r + 8 + sub;
        bool v0 = e0 < end, v1 = e1 < end;
        int s0 = src[v0 ? e0 : end - 1];
        int s1 = src[v1 ? e1 : end - 1];
        float lg0 = als[s0 * NH + hh] + aldv;
        float lg1 = als[s1 * NH + hh] + aldv;
        lg0 = lg0 > 0.f ? lg0 : 0.2f * lg0;
        lg1 = lg1 > 0.f ? lg1 : 0.2f * lg1;
        float w0 = v0 ? __expf(lg0) : 0.f;
        float w1 = v1 ? __expf(lg1) : 0.f;
        #pragma unroll
        for (int i = 0; i < 4; ++i) {
            int srcl = (2 * i + hf) * 8;
            int sv0   = __shfl(s0, srcl);
            float wv0 = __shfl(w0, srcl + hp);
            int sv1   = __shfl(s1, srcl);
            float wv1 = __shfl(w1, srcl + hp);
            float2 h0 = __half22float2(*(const __half2*)(&h1h[(size_t)sv0 * C1 + 2 * cp]));
            float2 h1v = __half22float2(*(const __half2*)(&h1h[(size_t)sv1 * C1 + 2 * cp]));
            accx += wv0 * h0.x + wv1 * h1v.x;
            accy += wv0 * h0.y + wv1 * h1v.y;
            den  += wv0 + wv1;
        }
    }
    accx += __shfl_xor(accx, 32);
    accy += __shfl_xor(accy, 32);
    den  += __shfl_xor(den, 32);
    float o0 = accx / den + b1[2 * cp];
    float o1 = accy / den + b1[2 * cp + 1];
    o0 = o0 > 0.f ? o0 : (__expf(o0) - 1.f);
    o1 = o1 > 0.f ? o1 : (__expf(o1) - 1.f);
    if (hf == 0)
        *(float2*)(&g1[(size_t)d * C1 + 2 * cp]) = make_float2(o0, o1);
}

// ---------------- K3: GEMM2 (64->16) + layer-2 logits ----------------
__global__ __launch_bounds__(256) void k_gemm2(const float* __restrict__ g1,
                                               const float* __restrict__ W2,
                                               const float* __restrict__ as2,
                                               const float* __restrict__ ad2,
                                               float* __restrict__ h2,
                                               float* __restrict__ als2,
                                               float* __restrict__ ald2) {
    __shared__ float w2s[C1][NC];
    __shared__ float hact[16][C1 + 4];
    int tid = threadIdx.x;
    for (int i = tid; i < C1 * NC; i += 256) w2s[i >> 4][i & 15] = W2[i];
    int ln = tid >> 4, j = tid & 15;
    int n = blockIdx.x * 16 + ln;
    if (n < NN) {
        float4 v = *(const float4*)(&g1[(size_t)n * C1 + j * 4]);
        *(float4*)(&hact[ln][j * 4]) = v;
    }
    __syncthreads();
    if (n < NN) {
        float sum = 0.f;
        #pragma unroll
        for (int c = 0; c < C1; ++c) sum += hact[ln][c] * w2s[c][j];
        h2[(size_t)n * NC + j] = sum;
        float ps = sum * as2[j], pd = sum * ad2[j];
        #pragma unroll
        for (int w = 1; w < 16; w <<= 1) {
            ps += __shfl_xor(ps, w);
            pd += __shfl_xor(pd, w);
        }
        if (j == 0) { als2[n] = ps; ald2[n] = pd; }
    }
}

// ------- K4: layer-2 aggregation, 16 lanes/dst, 4-edge ILP + log_softmax ---
__global__ __launch_bounds__(256) void k_agg2(const int* __restrict__ offs,
                                              const int* __restrict__ src,
                                              const float* __restrict__ h2,
                                              const float* __restrict__ als2,
                                              const float* __restrict__ ald2,
                                              const float* __restrict__ b2,
                                              float* __restrict__ out) {
    int d = blockIdx.x * 16 + (threadIdx.x >> 4);
    if (d >= NN) return;
    int c = threadIdx.x & 15;
    int beg = offs[d], end = offs[d + 1];
    float aldv = ald2[d];
    float acc = 0.f, den = 0.f;
    for (int r = beg; r < end; r += 4) {
        int e1 = r + 1, e2 = r + 2, e3 = r + 3;
        bool v1 = e1 < end, v2 = e2 < end, v3 = e3 < end;
        int s0 = src[r];
        int s1 = src[v1 ? e1 : end - 1];
        int s2 = src[v2 ? e2 : end - 1];
        int s3 = src[v3 ? e3 : end - 1];
        float l0 = als2[s0] + aldv;
        float l1 = als2[s1] + aldv;
        float l2 = als2[s2] + aldv;
        float l3 = als2[s3] + aldv;
        l0 = l0 > 0.f ? l0 : 0.2f * l0;
        l1 = l1 > 0.f ? l1 : 0.2f * l1;
        l2 = l2 > 0.f ? l2 : 0.2f * l2;
        l3 = l3 > 0.f ? l3 : 0.2f * l3;
        float w0 = __expf(l0);
        float w1 = v1 ? __expf(l1) : 0.f;
        float w2 = v2 ? __expf(l2) : 0.f;
        float w3 = v3 ? __expf(l3) : 0.f;
        float f0 = h2[(size_t)s0 * NC + c];
        float f1 = h2[(size_t)s1 * NC + c];
        float f2 = h2[(size_t)s2 * NC + c];
        float f3 = h2[(size_t)s3 * NC + c];
        acc += w0 * f0 + w1 * f1 + w2 * f2 + w3 * f3;
        den += w0 + w1 + w2 + w3;
    }
    float o = acc / den + b2[c];
    float m = o;
    #pragma unroll
    for (int w = 1; w < 16; w <<= 1) m = fmaxf(m, __shfl_xor(m, w));
    float ex = __expf(o - m);
    float sm = ex;
    #pragma unroll
    for (int w = 1; w < 16; w <<= 1) sm += __shfl_xor(sm, w);
    out[(size_t)d * NC + c] = o - m - __logf(sm);
}

extern "C" void kernel_launch(void* const* d_in, const int* in_sizes, int n_in,
                              void* d_out, int out_size, void* d_ws, size_t ws_size,
                              hipStream_t stream) {
    const float* x   = (const float*)d_in[0];
    const int*   ei  = (const int*)  d_in[1];
    const float* W1  = (const float*)d_in[2];
    const float* as1 = (const float*)d_in[3];
    const float* ad1 = (const float*)d_in[4];
    const float* b1  = (const float*)d_in[5];
    const float* W2  = (const float*)d_in[6];
    const float* as2 = (const float*)d_in[7];
    const float* ad2 = (const float*)d_in[8];
    const float* b2  = (const float*)d_in[9];
    float* ws  = (float*)d_ws;
    float* out = (float*)d_out;

    __half* h1h = (__half*)(ws + OFF_H1H);
    float* g1   = ws + OFF_G1;
    float* als1 = ws + OFF_ALS1;
    float* ald1 = ws + OFF_ALD1;
    float* h2   = ws + OFF_H2;
    float* als2 = ws + OFF_ALS2;
    float* ald2 = ws + OFF_ALD2;
    int* H      = (int*)(ws + OFF_HM);
    int* basek  = (int*)(ws + OFF_BASEK);
    int* bbase  = (int*)(ws + OFF_BBASE);
    int* offs   = (int*)(ws + OFF_OFFS);
    int* ssrc   = (int*)(ws + OFF_SRC);
    int* stage  = (int*)(ws + OFF_G1);   // aliases g1 (dead before k_agg1 writes g1)

    k_gemm1   <<<(NN + 63) / 64, 256, 0, stream>>>(x, W1, as1, ad1, h1h, als1, ald1);
    k_rh      <<<CH,             256, 0, stream>>>(ei, H);
    k_rsA     <<<NCB,            256, 0, stream>>>(H, basek, bbase + NCB + 2 /*btot*/);
    k_rsB     <<<1,               64, 0, stream>>>(bbase + NCB + 2, bbase, offs);
    k_rscatter<<<CH,             256, 0, stream>>>(ei, basek, bbase, stage);
    k_fsort   <<<NCB,            256, 0, stream>>>(stage, bbase, offs, ssrc);
    k_agg1    <<<(NN + 3) / 4,   256, 0, stream>>>(offs, ssrc, h1h, als1, ald1, b1, g1);
    k_gemm2   <<<(NN + 15) / 16, 256, 0, stream>>>(g1, W2, as2, ad2, h2, als2, ald2);
    k_agg2    <<<(NN + 15) / 16, 256, 0, stream>>>(offs, ssrc, h2, als2, ald2, b2, out);
}

// Round 8
// 142.653 us; speedup vs baseline: 1.3009x; 1.0433x over previous
//
#include <hip/hip_runtime.h>
#include <hip/hip_fp16.h>

#define NN   50000
#define FIN  256
#define C1   64        // HEADS*HID
#define NH   8
#define NC   16
#define NE   1600000
#define NTOT (NE + NN)

#define CH   256                        // pass-1 chunks
#define EPC  ((NTOT + CH - 1) / CH)     // 6446 edges per chunk
#define NCB  196                        // coarse buckets: dst>>8
#define GB1  ((NN + 63) / 64)           // 782 gemm1 blocks

typedef _Float16 half8 __attribute__((ext_vector_type(8)));
typedef _Float16 half4 __attribute__((ext_vector_type(4)));
typedef float f32x4 __attribute__((ext_vector_type(4)));

// ---- workspace layout (float-indexed), 36.0 MB ----
#define OFF_H1H   0          // fp16 h1 [NN*64 halves] = [0, 1.6M floats)
#define OFF_H2H   1600000    // fp16 h2 [NN*16 halves] = 400K floats
#define OFF_ALS2  2000000    // f32 [NN]
#define OFF_ALD2  2050000    // f32 [NN]
#define OFF_STAGE 3200000    // int stage[NTOT] (sort staging)
#define OFF_ALS1  6400000    // f32 [NN*NH]
#define OFF_ALD1  6800000
#define OFF_HM    7200000    // int H[CH*NCB]
#define OFF_BASEK 7251000    // int basek[NCB*CH]
#define OFF_BBASE 7302000    // int bbase[NCB+1] (+btot scratch behind)
#define OFF_OFFS  7302400    // int offs[NN+1]
#define OFF_SRC   7352500    // int ssrc[NTOT]
// end = 9,002,500 floats = 36.0 MB

// ------- K1: [blocks 0..781] h1=x@W1 MFMA + fp16 store + logits epilogue
//         [blocks 782..1037] rh: per-chunk coarse histogram (independent)
__global__ __launch_bounds__(256) void k_g1rh(const float* __restrict__ x,
                                              const float* __restrict__ W1,
                                              const float* __restrict__ as1,
                                              const float* __restrict__ ad1,
                                              __half* __restrict__ h1h,
                                              float* __restrict__ als,
                                              float* __restrict__ ald,
                                              const int* __restrict__ ei,
                                              int* __restrict__ H) {
    __shared__ _Float16 wsT[64][264];   // [col][k]
    __shared__ _Float16 xs[64][40];
    __shared__ int lh[NCB];
    const int tid = threadIdx.x;

    if (blockIdx.x >= GB1) {            // ---- rh branch ----
        int k = blockIdx.x - GB1;
        for (int i = tid; i < NCB; i += 256) lh[i] = 0;
        __syncthreads();
        int e0 = k * EPC, e1 = min(e0 + EPC, NTOT);
        for (int e = e0 + tid; e < e1; e += 256) {
            int d = (e < NE) ? ei[NE + e] : (e - NE);
            atomicAdd(&lh[d >> 8], 1);
        }
        __syncthreads();
        for (int i = tid; i < NCB; i += 256) H[k * NCB + i] = lh[i];
        return;
    }

    // ---- gemm1 branch ----
    const int r0 = blockIdx.x * 64;
    // wsT fill: thread t -> col c=t&63, k-octet base t>>6; 8 half8 writes
    {
        int c = tid & 63, kb = tid >> 6;
        #pragma unroll
        for (int j = 0; j < 8; ++j) {
            int k8 = kb + 4 * j;            // 0..31
            half8 hv;
            #pragma unroll
            for (int u = 0; u < 8; ++u)
                hv[u] = (_Float16)W1[(size_t)(k8 * 8 + u) * C1 + c];
            *(half8*)(&wsT[c][k8 * 8]) = hv;
        }
    }

    const int lane = tid & 63;
    const int wv   = tid >> 6;
    const int colb = lane & 15;
    const int rgrp = lane >> 4;
    f32x4 acc[4] = {};
    const int srow = tid >> 2;
    const int sq   = tid & 3;
    for (int k0 = 0; k0 < FIN; k0 += 32) {
        __syncthreads();
        {
            int grow = r0 + srow;
            float4 v0 = make_float4(0.f,0.f,0.f,0.f), v1 = v0;
            if (grow < NN) {
                const float4* xp = (const float4*)(&x[(size_t)grow * FIN + k0 + sq * 8]);
                v0 = xp[0]; v1 = xp[1];
            }
            half8 hv;
            hv[0]=(_Float16)v0.x; hv[1]=(_Float16)v0.y; hv[2]=(_Float16)v0.z; hv[3]=(_Float16)v0.w;
            hv[4]=(_Float16)v1.x; hv[5]=(_Float16)v1.y; hv[6]=(_Float16)v1.z; hv[7]=(_Float16)v1.w;
            *(half8*)(&xs[srow][sq * 8]) = hv;
        }
        __syncthreads();
        half8 a = *(half8*)(&xs[wv * 16 + colb][rgrp * 8]);
        #pragma unroll
        for (int ct = 0; ct < 4; ++ct) {
            half8 b = *(half8*)(&wsT[ct * 16 + colb][k0 + rgrp * 8]);
            acc[ct] = __builtin_amdgcn_mfma_f32_16x16x32_f16(a, b, acc[ct], 0, 0, 0);
        }
    }

    float a_s[4], a_d[4];
    #pragma unroll
    for (int ct = 0; ct < 4; ++ct) { a_s[ct] = as1[ct * 16 + colb]; a_d[ct] = ad1[ct * 16 + colb]; }
    #pragma unroll
    for (int j = 0; j < 4; ++j) {
        int row = r0 + wv * 16 + rgrp * 4 + j;
        bool rv = row < NN;
        #pragma unroll
        for (int ct = 0; ct < 4; ++ct) {
            if (rv) h1h[(size_t)row * C1 + ct * 16 + colb] = __float2half(acc[ct][j]);
            float p = acc[ct][j] * a_s[ct];
            p += __shfl_xor(p, 1); p += __shfl_xor(p, 2); p += __shfl_xor(p, 4);
            float q = acc[ct][j] * a_d[ct];
            q += __shfl_xor(q, 1); q += __shfl_xor(q, 2); q += __shfl_xor(q, 4);
            if (rv && (lane & 7) == 0) {
                int head = ct * 2 + (colb >> 3);
                als[row * NH + head] = p;
                ald[row * NH + head] = q;
            }
        }
    }
}

// ======== deterministic 2-pass counting sort (no global atomics) =========
__global__ __launch_bounds__(256) void k_rsA(const int* __restrict__ H,
                                             int* __restrict__ basek,
                                             int* __restrict__ btot) {
    __shared__ int sc[CH];
    int b = blockIdx.x, t = threadIdx.x;
    int v = H[t * NCB + b];
    sc[t] = v;
    __syncthreads();
    for (int s = 1; s < CH; s <<= 1) {
        int u = (t >= s) ? sc[t - s] : 0;
        __syncthreads();
        sc[t] += u;
        __syncthreads();
    }
    basek[b * CH + t] = sc[t] - v;
    if (t == CH - 1) btot[b] = sc[t];
}

__global__ __launch_bounds__(64) void k_rsB(int* __restrict__ btot,
                                            int* __restrict__ bbase,
                                            int* __restrict__ offs) {
    if (threadIdx.x == 0) {
        int run = 0;
        for (int b = 0; b < NCB; ++b) {
            bbase[b] = run;
            run += btot[b];
        }
        bbase[NCB] = run;
        offs[NN] = NTOT;
    }
}

__global__ __launch_bounds__(256) void k_rscatter(const int* __restrict__ ei,
                                                  const int* __restrict__ basek,
                                                  const int* __restrict__ bbase,
                                                  int* __restrict__ stage) {
    __shared__ int lcur[NCB];
    int k = blockIdx.x;
    for (int i = threadIdx.x; i < NCB; i += 256)
        lcur[i] = bbase[i] + basek[i * CH + k];
    __syncthreads();
    int e0 = k * EPC, e1 = min(e0 + EPC, NTOT);
    for (int e = e0 + threadIdx.x; e < e1; e += 256) {
        int s, d;
        if (e < NE) { s = ei[e]; d = ei[NE + e]; }
        else        { s = e - NE; d = s; }
        int pos = atomicAdd(&lcur[d >> 8], 1);
        stage[pos] = (s << 8) | (d & 255);
    }
}

__global__ __launch_bounds__(256) void k_fsort(const int* __restrict__ stage,
                                               const int* __restrict__ bbase,
                                               int* __restrict__ offs,
                                               int* __restrict__ ssrc) {
    __shared__ int lc[256];
    __shared__ int ls[256];
    __shared__ int lcur[256];
    int b = blockIdx.x, t = threadIdx.x;
    int base = bbase[b];
    int n = bbase[b + 1] - base;
    lc[t] = 0;
    __syncthreads();
    const int* sp = &stage[base];
    for (int i = t; i < n; i += 256) atomicAdd(&lc[sp[i] & 255], 1);
    __syncthreads();
    int v = lc[t];
    ls[t] = v;
    __syncthreads();
    for (int s = 1; s < 256; s <<= 1) {
        int u = (t >= s) ? ls[t - s] : 0;
        __syncthreads();
        ls[t] += u;
        __syncthreads();
    }
    int excl = ls[t] - v;
    int d = b * 256 + t;
    if (d < NN) offs[d] = base + excl;
    lcur[t] = base + excl;
    __syncthreads();
    for (int i = t; i < n; i += 256) {
        int u = sp[i];
        int pos = atomicAdd(&lcur[u & 255], 1);
        ssrc[pos] = u >> 8;
    }
}

// ------- K2: layer-1 aggregation (quarter half4 gathers) + fused GEMM2 ----
// wave per dst. lane l: q=l>>4, lc=l&15. Gathers channels 4lc..4lc+3 (head lc>>1)
// of edge slots {4i+q}; weight duty: lane computes w for slots l>>3, (l>>3)+8, head l&7.
// Epilogue: normalize+bias+ELU, then per-wave GEMM2 (64->16) + logits2, h2 in fp16.
__global__ __launch_bounds__(256) void k_agg1(const int* __restrict__ offs,
                                              const int* __restrict__ src,
                                              const __half* __restrict__ h1h,
                                              const float* __restrict__ als,
                                              const float* __restrict__ ald,
                                              const float* __restrict__ b1,
                                              const float* __restrict__ W2,
                                              const float* __restrict__ as2,
                                              const float* __restrict__ ad2,
                                              __half* __restrict__ h2h,
                                              float* __restrict__ als2,
                                              float* __restrict__ ald2) {
    __shared__ float lds_w2[C1][17];    // padded: 4-way -> 2-way (free)
    __shared__ float lds_g[4][C1];
    int tid = threadIdx.x;
    #pragma unroll
    for (int i = tid; i < C1 * NC; i += 256) lds_w2[i >> 4][i & 15] = W2[i];
    __syncthreads();

    int wv = tid >> 6;
    int d = blockIdx.x * 4 + wv;
    if (d >= NN) return;
    const int l  = tid & 63;
    const int q  = l >> 4, lc = l & 15;
    const int hg = lc >> 1;                 // head of gathered channels
    const int sub = l >> 3, hw = l & 7;     // weight duty
    const int lane_a = (q << 3) | hg;       // weight source lanes
    const int lane_b = lane_a + 32;
    int beg = offs[d], end = offs[d + 1];
    float aldv = ald[d * NH + hw];
    f32x4 acc = {0.f, 0.f, 0.f, 0.f};
    float den = 0.f;

    for (int r = beg; r < end; r += 16) {
        int e0 = r + sub, e1 = e0 + 8;
        bool v0 = e0 < end, v1 = e1 < end;
        int s0 = src[v0 ? e0 : end - 1];
        int s1 = src[v1 ? e1 : end - 1];
        float lg0 = als[s0 * NH + hw] + aldv;
        float lg1 = als[s1 * NH + hw] + aldv;
        lg0 = lg0 > 0.f ? lg0 : 0.2f * lg0;
        lg1 = lg1 > 0.f ? lg1 : 0.2f * lg1;
        float w0 = v0 ? __expf(lg0) : 0.f;
        float w1 = v1 ? __expf(lg1) : 0.f;
        #pragma unroll
        for (int i = 0; i < 4; ++i) {
            int srcl = (i & 1) ? lane_b : lane_a;   // slot 4i+q lives at lane ((4i+q)&7)*8+hg
            int sv   = __shfl((i < 2) ? s0 : s1, srcl);
            float wvv= __shfl((i < 2) ? w0 : w1, srcl);
            half4 hv = *(const half4*)(&h1h[(size_t)sv * C1 + 4 * lc]);
            acc[0] += wvv * (float)hv[0];
            acc[1] += wvv * (float)hv[1];
            acc[2] += wvv * (float)hv[2];
            acc[3] += wvv * (float)hv[3];
            den += wvv;
        }
    }
    #pragma unroll
    for (int k = 0; k < 4; ++k) {
        acc[k] += __shfl_xor(acc[k], 16);
        acc[k] += __shfl_xor(acc[k], 32);
    }
    den += __shfl_xor(den, 16);
    den += __shfl_xor(den, 32);

    float g[4];
    #pragma unroll
    for (int k = 0; k < 4; ++k) {
        float o = acc[k] / den + b1[4 * lc + k];
        g[k] = o > 0.f ? o : (__expf(o) - 1.f);
    }
    if (q == 0) *(float4*)(&lds_g[wv][4 * lc]) = make_float4(g[0], g[1], g[2], g[3]);
    // wave-internal LDS: DS ops are wave-ordered; no barrier needed.
    float h2p = 0.f;
    #pragma unroll
    for (int m = 0; m < 16; ++m)
        h2p += lds_g[wv][q * 16 + m] * lds_w2[q * 16 + m][lc];
    h2p += __shfl_xor(h2p, 16);
    h2p += __shfl_xor(h2p, 32);
    if (l < 16) h2h[(size_t)d * NC + lc] = __float2half(h2p);
    float ps = h2p * as2[lc], pd = h2p * ad2[lc];
    ps += __shfl_xor(ps, 1); ps += __shfl_xor(ps, 2);
    ps += __shfl_xor(ps, 4); ps += __shfl_xor(ps, 8);
    pd += __shfl_xor(pd, 1); pd += __shfl_xor(pd, 2);
    pd += __shfl_xor(pd, 4); pd += __shfl_xor(pd, 8);
    if (l == 0) { als2[d] = ps; ald2[d] = pd; }
}

// ------- K4: layer-2 aggregation (fp16 h2), 16 lanes/dst, 4-edge ILP ------
__global__ __launch_bounds__(256) void k_agg2(const int* __restrict__ offs,
                                              const int* __restrict__ src,
                                              const __half* __restrict__ h2h,
                                              const float* __restrict__ als2,
                                              const float* __restrict__ ald2,
                                              const float* __restrict__ b2,
                                              float* __restrict__ out) {
    int d = blockIdx.x * 16 + (threadIdx.x >> 4);
    if (d >= NN) return;
    int c = threadIdx.x & 15;
    int beg = offs[d], end = offs[d + 1];
    float aldv = ald2[d];
    float acc = 0.f, den = 0.f;
    for (int r = beg; r < end; r += 4) {
        int e1 = r + 1, e2 = r + 2, e3 = r + 3;
        bool v1 = e1 < end, v2 = e2 < end, v3 = e3 < end;
        int s0 = src[r];
        int s1 = src[v1 ? e1 : end - 1];
        int s2 = src[v2 ? e2 : end - 1];
        int s3 = src[v3 ? e3 : end - 1];
        float l0 = als2[s0] + aldv;
        float l1 = als2[s1] + aldv;
        float l2 = als2[s2] + aldv;
        float l3 = als2[s3] + aldv;
        l0 = l0 > 0.f ? l0 : 0.2f * l0;
        l1 = l1 > 0.f ? l1 : 0.2f * l1;
        l2 = l2 > 0.f ? l2 : 0.2f * l2;
        l3 = l3 > 0.f ? l3 : 0.2f * l3;
        float w0 = __expf(l0);
        float w1 = v1 ? __expf(l1) : 0.f;
        float w2 = v2 ? __expf(l2) : 0.f;
        float w3 = v3 ? __expf(l3) : 0.f;
        float f0 = __half2float(h2h[(size_t)s0 * NC + c]);
        float f1 = __half2float(h2h[(size_t)s1 * NC + c]);
        float f2 = __half2float(h2h[(size_t)s2 * NC + c]);
        float f3 = __half2float(h2h[(size_t)s3 * NC + c]);
        acc += w0 * f0 + w1 * f1 + w2 * f2 + w3 * f3;
        den += w0 + w1 + w2 + w3;
    }
    float o = acc / den + b2[c];
    float m = o;
    #pragma unroll
    for (int w = 1; w < 16; w <<= 1) m = fmaxf(m, __shfl_xor(m, w));
    float ex = __expf(o - m);
    float sm = ex;
    #pragma unroll
    for (int w = 1; w < 16; w <<= 1) sm += __shfl_xor(sm, w);
    out[(size_t)d * NC + c] = o - m - __logf(sm);
}

extern "C" void kernel_launch(void* const* d_in, const int* in_sizes, int n_in,
                              void* d_out, int out_size, void* d_ws, size_t ws_size,
                              hipStream_t stream) {
    const float* x   = (const float*)d_in[0];
    const int*   ei  = (const int*)  d_in[1];
    const float* W1  = (const float*)d_in[2];
    const float* as1 = (const float*)d_in[3];
    const float* ad1 = (const float*)d_in[4];
    const float* b1  = (const float*)d_in[5];
    const float* W2  = (const float*)d_in[6];
    const float* as2 = (const float*)d_in[7];
    const float* ad2 = (const float*)d_in[8];
    const float* b2  = (const float*)d_in[9];
    float* ws  = (float*)d_ws;
    float* out = (float*)d_out;

    __half* h1h = (__half*)(ws + OFF_H1H);
    __half* h2h = (__half*)(ws + OFF_H2H);
    float* als1 = ws + OFF_ALS1;
    float* ald1 = ws + OFF_ALD1;
    float* als2 = ws + OFF_ALS2;
    float* ald2 = ws + OFF_ALD2;
    int* H      = (int*)(ws + OFF_HM);
    int* basek  = (int*)(ws + OFF_BASEK);
    int* bbase  = (int*)(ws + OFF_BBASE);
    int* offs   = (int*)(ws + OFF_OFFS);
    int* ssrc   = (int*)(ws + OFF_SRC);
    int* stage  = (int*)(ws + OFF_STAGE);

    k_g1rh    <<<GB1 + CH,       256, 0, stream>>>(x, W1, as1, ad1, h1h, als1, ald1, ei, H);
    k_rsA     <<<NCB,            256, 0, stream>>>(H, basek, bbase + NCB + 2 /*btot*/);
    k_rsB     <<<1,               64, 0, stream>>>(bbase + NCB + 2, bbase, offs);
    k_rscatter<<<CH,             256, 0, stream>>>(ei, basek, bbase, stage);
    k_fsort   <<<NCB,            256, 0, stream>>>(stage, bbase, offs, ssrc);
    k_agg1    <<<(NN + 3) / 4,   256, 0, stream>>>(offs, ssrc, h1h, als1, ald1, b1,
                                                   W2, as2, ad2, h2h, als2, ald2);
    k_agg2    <<<(NN + 15) / 16, 256, 0, stream>>>(offs, ssrc, h2h, als2, ald2, b2, out);
}